// Round 7
// baseline (157.926 us; speedup 1.0000x reference)
//
#include <hip/hip_runtime.h>
#include <cstdint>
#include <cstddef>

typedef short bfrag  __attribute__((ext_vector_type(8)));   // 8 bf16 (4 VGPR)
typedef float facc   __attribute__((ext_vector_type(4)));   // 4 f32
typedef float f32x16 __attribute__((ext_vector_type(16)));  // 32x32 acc
typedef float f32x4v __attribute__((ext_vector_type(4)));   // indexable float4

namespace {
constexpr int B = 128, N = 2048, A = 16, M = 64, D = 16;
constexpr int NA = N * A;            // 32768 (GEMM K)
constexpr int MD = M * D;            // 1024  (GEMM N)
constexpr size_t C_ELEMS = (size_t)B * MD;  // 131072
}

static __device__ __forceinline__ ushort f2bf(float x) {  // RNE f32->bf16
    uint u = __float_as_uint(x);
    u += 0x7fffu + ((u >> 16) & 1u);
    return (ushort)(u >> 16);
}
static __device__ __forceinline__ bfrag ld_frag16(const ushort* p) {  // 16B-aligned
    union { uint4 q; bfrag v; } u;
    u.q = *(const uint4*)p;
    return u.v;
}
static __device__ __forceinline__ bfrag ld_frag4(const ushort* p) {   // 4B-aligned
    const uint* q = (const uint*)p;
    union { uint a[4]; bfrag v; } u;
    u.a[0] = q[0]; u.a[1] = q[1]; u.a[2] = q[2]; u.a[3] = q[3];
    return u.v;
}

// ---------------------------------------------------------------------------
// k0: convert in fp32 -> bf16 (same [b][na] layout). 8 elems/thread.
// ---------------------------------------------------------------------------
__global__ __launch_bounds__(256) void k0_cvt(const float* __restrict__ in,
                                              ushort* __restrict__ inb) {
    const size_t i = (size_t)blockIdx.x * 256 + threadIdx.x;  // 524288 total
    const float4 a = *(const float4*)(in + i * 8);
    const float4 c = *(const float4*)(in + i * 8 + 4);
    union { ushort s[8]; uint4 q; } p;
    p.s[0] = f2bf(a.x); p.s[1] = f2bf(a.y); p.s[2] = f2bf(a.z); p.s[3] = f2bf(a.w);
    p.s[4] = f2bf(c.x); p.s[5] = f2bf(c.y); p.s[6] = f2bf(c.z); p.s[7] = f2bf(c.w);
    *(uint4*)(inb + i * 8) = p.q;
}

// ---------------------------------------------------------------------------
// k1: split-K bf16 MFMA GEMM. part[chunk][b][md] = sum_{na in chunk} in*w
// + (dump) side-product: wT[md][na] bf16 (w_t LDS tile is already this
// layout — 16 ds_read_b32 + 4 dwordx4 stores per thread per KT).
// ---------------------------------------------------------------------------
__global__ __launch_bounds__(512, 2) void k1_mfma(const float* __restrict__ in,
                                                  const float* __restrict__ w,
                                                  float* __restrict__ part,
                                                  ushort* __restrict__ wT,
                                                  int nch, int dump) {
    const int mdg   = blockIdx.x;
    const int chunk = blockIdx.y;
    const int t     = threadIdx.x;
    const int nap   = NA / nch;
    const int nkt   = nap / 64;
    __shared__ __align__(16) ushort in_t[128 * 72];
    __shared__ __align__(16) ushort w_t[256 * 66];
    const int wv = t >> 6, tl = t & 63;
    const int wb = wv >> 2, wm = wv & 3;
    const int lr = tl & 15, hi = tl >> 4;

    facc acc[4][4];
    #pragma unroll
    for (int i = 0; i < 4; ++i)
        #pragma unroll
        for (int j = 0; j < 4; ++j) acc[i][j] = facc{0.f, 0.f, 0.f, 0.f};

    float4 pin[4], pw[8];
    const int ib  = t >> 4, ik = t & 15;
    const int wk  = t >> 6, wmd = t & 63;

    int na0 = chunk * nap;
    #pragma unroll
    for (int q = 0; q < 4; ++q)
        pin[q] = *(const float4*)(in + (size_t)(q * 32 + ib) * NA + na0 + ik * 4);
    #pragma unroll
    for (int q = 0; q < 8; ++q)
        pw[q] = *(const float4*)(w + (size_t)(na0 + q * 8 + wk) * MD + mdg * 256 + wmd * 4);

    for (int kt = 0; kt < nkt; ++kt) {
        __syncthreads();
        #pragma unroll
        for (int q = 0; q < 4; ++q) {
            union { ushort s[4]; uint2 u; } pk;
            pk.s[0] = f2bf(pin[q].x); pk.s[1] = f2bf(pin[q].y);
            pk.s[2] = f2bf(pin[q].z); pk.s[3] = f2bf(pin[q].w);
            *(uint2*)(&in_t[(q * 32 + ib) * 72 + ik * 4]) = pk.u;
        }
        #pragma unroll
        for (int q = 0; q < 8; ++q) {
            const int krow = q * 8 + wk;
            w_t[(wmd * 4 + 0) * 66 + krow] = f2bf(pw[q].x);
            w_t[(wmd * 4 + 1) * 66 + krow] = f2bf(pw[q].y);
            w_t[(wmd * 4 + 2) * 66 + krow] = f2bf(pw[q].z);
            w_t[(wmd * 4 + 3) * 66 + krow] = f2bf(pw[q].w);
        }
        __syncthreads();
        if (kt + 1 < nkt) {
            const int nan = na0 + 64;
            #pragma unroll
            for (int q = 0; q < 4; ++q)
                pin[q] = *(const float4*)(in + (size_t)(q * 32 + ib) * NA + nan + ik * 4);
            #pragma unroll
            for (int q = 0; q < 8; ++q)
                pw[q] = *(const float4*)(w + (size_t)(nan + q * 8 + wk) * MD + mdg * 256 + wmd * 4);
        }
        if (dump) {   // w_t[mdl][k] -> wT[mdg*256+mdl][na0+k]  (bf16)
            const int mdl = t >> 1, kh = t & 1;
            const uint* s32 = (const uint*)&w_t[mdl * 66 + kh * 32];  // 4B-aligned
            ushort* dst = wT + (size_t)(mdg * 256 + mdl) * NA + na0 + kh * 32;
            #pragma unroll
            for (int j = 0; j < 4; ++j) {
                uint4 o;
                o.x = s32[j * 4]; o.y = s32[j * 4 + 1];
                o.z = s32[j * 4 + 2]; o.w = s32[j * 4 + 3];
                *(uint4*)(dst + j * 8) = o;       // 16B-aligned
            }
        }
        #pragma unroll
        for (int ks = 0; ks < 2; ++ks) {
            bfrag af[4], bf[4];
            #pragma unroll
            for (int bt = 0; bt < 4; ++bt)
                af[bt] = ld_frag16(&in_t[(wb * 64 + bt * 16 + lr) * 72 + ks * 32 + hi * 8]);
            #pragma unroll
            for (int mt = 0; mt < 4; ++mt)
                bf[mt] = ld_frag4(&w_t[(wm * 64 + mt * 16 + lr) * 66 + ks * 32 + hi * 8]);
            #pragma unroll
            for (int bt = 0; bt < 4; ++bt)
                #pragma unroll
                for (int mt = 0; mt < 4; ++mt)
                    acc[bt][mt] = __builtin_amdgcn_mfma_f32_16x16x32_bf16(
                        af[bt], bf[mt], acc[bt][mt], 0, 0, 0);
        }
        na0 += 64;
    }
    #pragma unroll
    for (int bt = 0; bt < 4; ++bt)
        #pragma unroll
        for (int mt = 0; mt < 4; ++mt) {
            const int b  = wb * 64 + bt * 16 + hi * 4;
            const int md = mdg * 256 + wm * 64 + mt * 16 + lr;
            #pragma unroll
            for (int r = 0; r < 4; ++r)
                part[((size_t)chunk * B + b + r) * MD + md] = acc[bt][mt][r];
        }
}

// ---------------------------------------------------------------------------
// k2: reduce partials -> v_raw -> squash -> v_sq (ws); LayerNorm -> out_v
// ---------------------------------------------------------------------------
__global__ __launch_bounds__(256) void k2_squash_ln(const float* __restrict__ part,
                                                    const float* __restrict__ gamma,
                                                    const float* __restrict__ beta,
                                                    float* __restrict__ v_sq,
                                                    float* __restrict__ out_v,
                                                    int nch) {
    const int idx = blockIdx.x * 256 + threadIdx.x;
    const int d   = idx & 15;
    float s = 0.f;
    for (int c = 0; c < nch; ++c) s += part[(size_t)c * C_ELEMS + idx];
    const float v = s * (1.0f / 64.0f);
    float sq = v * v;
    #pragma unroll
    for (int off = 1; off < 16; off <<= 1) sq += __shfl_xor(sq, off, 16);
    const float f  = sqrtf(sq) / (1.0f + sq);
    const float vs = v * f;
    v_sq[idx] = vs;
    float mu = vs;
    #pragma unroll
    for (int off = 1; off < 16; off <<= 1) mu += __shfl_xor(mu, off, 16);
    mu *= (1.0f / 16.0f);
    const float dd = vs - mu;
    float var = dd * dd;
    #pragma unroll
    for (int off = 1; off < 16; off <<= 1) var += __shfl_xor(var, off, 16);
    var *= (1.0f / 16.0f);
    out_v[idx] = dd / sqrtf(var + 1e-5f) * gamma[d] + beta[d];
}

// ---------------------------------------------------------------------------
// k3 v7 (k3_direct): staging-free. LDS = 0, barriers = 0.
// A-frag (w^T rows=(mj,d), K=a) = contiguous 16B of wT[md][na] per lane;
// B-frag (in^T cols=b, K=a)     = contiguous 16B of inb[b][na] per lane.
// Per n: 5 global b128 loads -> 4 MFMA 32x32x16 -> 64 FMA vs reg vsq ->
// 8 shfl_xor(32) -> 1 float4 store. 1-deep reg prefetch of n+1.
// grid (8 mg, 64 nseg of 32n), 256 thr = 4 waves = 4 b-groups.
// C layout (HW-verified R5/R6): col=lane&31=b, row=(reg&3)+8*(reg>>2)+4*l5.
// ---------------------------------------------------------------------------
__global__ __launch_bounds__(256) void k3_direct(const ushort* __restrict__ wT,
                                                 const ushort* __restrict__ inb,
                                                 const float* __restrict__ vsq,
                                                 float* __restrict__ qk) {
    const int m0 = blockIdx.x * 8;
    const int n0 = blockIdx.y * 32;
    const int t  = threadIdx.x;
    const int wv = t >> 6, lane = t & 63;
    const int lc = lane & 31, l5 = lane >> 5;
    const int b  = wv * 32 + lc;

    f32x4v vr[8][2];   // vr[mm][h][e] = vsq[b][m0+mm][h*8 + 4*l5 + e]
    #pragma unroll
    for (int mm = 0; mm < 8; ++mm) {
        vr[mm][0] = *(const f32x4v*)(vsq + ((size_t)b * M + m0 + mm) * D + 4 * l5);
        vr[mm][1] = *(const f32x4v*)(vsq + ((size_t)b * M + m0 + mm) * D + 8 + 4 * l5);
    }
    const ushort* arow = wT + ((size_t)(m0 + (lc >> 4)) * 16 + (lc & 15)) * NA + l5 * 8;
    const ushort* brow = inb + (size_t)b * NA + l5 * 8;

    bfrag ac0, ac1, ac2, ac3, bc;
    ac0 = ld_frag16(arow + (size_t)0 * 32 * NA + n0 * 16);
    ac1 = ld_frag16(arow + (size_t)1 * 32 * NA + n0 * 16);
    ac2 = ld_frag16(arow + (size_t)2 * 32 * NA + n0 * 16);
    ac3 = ld_frag16(arow + (size_t)3 * 32 * NA + n0 * 16);
    bc  = ld_frag16(brow + n0 * 16);

    for (int i = 0; i < 32; ++i) {
        bfrag an0, an1, an2, an3, bn;
        if (i + 1 < 32) {                         // prefetch n+1 into regs
            const int nx = (n0 + i + 1) * 16;
            an0 = ld_frag16(arow + (size_t)0 * 32 * NA + nx);
            an1 = ld_frag16(arow + (size_t)1 * 32 * NA + nx);
            an2 = ld_frag16(arow + (size_t)2 * 32 * NA + nx);
            an3 = ld_frag16(arow + (size_t)3 * 32 * NA + nx);
            bn  = ld_frag16(brow + nx);
        }
        const int n = n0 + i;
        float out4[4];
        bfrag aa[4] = {ac0, ac1, ac2, ac3};
        #pragma unroll
        for (int mp = 0; mp < 4; ++mp) {
            f32x16 c = {};
            c = __builtin_amdgcn_mfma_f32_32x32x16_bf16(aa[mp], bc, c, 0, 0, 0);
            #pragma unroll
            for (int mj = 0; mj < 2; ++mj) {
                float s = 0.f;
                #pragma unroll
                for (int rr = 0; rr < 8; ++rr)
                    s += c[mj * 8 + rr] * vr[mp * 2 + mj][rr >> 2][rr & 3];
                s += __shfl_xor(s, 32);           // add other d-half
                if ((mp >> 1) == l5) out4[(mp & 1) * 2 + mj] = s;
            }
        }
        *(float4*)(qk + ((size_t)b * N + n) * M + m0 + l5 * 4) =
            float4{out4[0], out4[1], out4[2], out4[3]};
        if (i + 1 < 32) { ac0 = an0; ac1 = an1; ac2 = an2; ac3 = an3; bc = bn; }
    }
}

// ---------------------------------------------------------------------------
// k3 v6 fallback (if ws too small for wT): R6's LDS-staged version.
// ---------------------------------------------------------------------------
__global__ __launch_bounds__(512, 4) void k3_mfma3(const float* __restrict__ in,
                                                   const float* __restrict__ w,
                                                   const float* __restrict__ vsq,
                                                   float* __restrict__ qk) {
    constexpr int WP = 24;
    const int m0 = blockIdx.x * 8;
    const int n0 = blockIdx.y * 16;
    const int t  = threadIdx.x;
    const int wv = t >> 6;
    const int nh = wv >> 2, bg = wv & 3;
    const int lane = t & 63;
    const int lc = lane & 31, l5 = lane >> 5;
    const int b  = bg * 32 + lc;
    __shared__ __align__(16) ushort wt[2][2][4 * 32 * WP];
    __shared__ __align__(16) ushort it[2][2][128 * WP];
    f32x4v vr[8][2];
    #pragma unroll
    for (int mm = 0; mm < 8; ++mm) {
        vr[mm][0] = *(const f32x4v*)(vsq + ((size_t)b * M + m0 + mm) * D + 4 * l5);
        vr[mm][1] = *(const f32x4v*)(vsq + ((size_t)b * M + m0 + mm) * D + 8 + 4 * l5);
    }
    const int s_nn = t >> 8, r = t & 255;
    const int wa1 = r & 7, wd4 = (r >> 3) & 3, wm_ = r >> 5;
    const int ib_ = r >> 1, iq = r & 1;
    float4 pw[2], pi[2];
    auto ldg = [&](int ph) {
        const int n = n0 + ph * 2 + s_nn;
        #pragma unroll
        for (int j = 0; j < 2; ++j)
            pw[j] = *(const float4*)(
                w + ((size_t)(n * A + wa1 * 2 + j) * M + m0 + wm_) * D + wd4 * 4);
        #pragma unroll
        for (int j = 0; j < 2; ++j)
            pi[j] = *(const float4*)(in + (size_t)ib_ * NA + n * A + iq * 8 + j * 4);
    };
    auto stg = [&](int p) {
        ushort* wb_ = &wt[p][s_nn][((wm_ >> 1) * 32 + (wm_ & 1) * 16) * WP];
        #pragma unroll
        for (int k = 0; k < 4; ++k) {
            union { ushort s[2]; uint u; } v;
            v.s[0] = f2bf(pw[0][k]);
            v.s[1] = f2bf(pw[1][k]);
            *(uint*)(&wb_[(wd4 * 4 + k) * WP + wa1 * 2]) = v.u;
        }
        union { ushort s[8]; uint4 q; } pk;
        #pragma unroll
        for (int j = 0; j < 2; ++j) {
            pk.s[j * 4 + 0] = f2bf(pi[j].x); pk.s[j * 4 + 1] = f2bf(pi[j].y);
            pk.s[j * 4 + 2] = f2bf(pi[j].z); pk.s[j * 4 + 3] = f2bf(pi[j].w);
        }
        *(uint4*)(&it[p][s_nn][ib_ * WP + iq * 8]) = pk.q;
    };
    ldg(0); stg(0); ldg(1);
    __syncthreads();
    for (int ph = 0; ph < 8; ++ph) {
        const int p = ph & 1;
        if (ph < 7) stg(p ^ 1);
        if (ph < 6) ldg(ph + 2);
        const int n = n0 + ph * 2 + nh;
        const bfrag bf = ld_frag16(&it[p][nh][b * WP + l5 * 8]);
        float out4[4];
        #pragma unroll
        for (int mp = 0; mp < 4; ++mp) {
            const bfrag af = ld_frag16(&wt[p][nh][(mp * 32 + lc) * WP + l5 * 8]);
            f32x16 c = {};
            c = __builtin_amdgcn_mfma_f32_32x32x16_bf16(af, bf, c, 0, 0, 0);
            #pragma unroll
            for (int mj = 0; mj < 2; ++mj) {
                float s = 0.f;
                #pragma unroll
                for (int rr = 0; rr < 8; ++rr)
                    s += c[mj * 8 + rr] * vr[mp * 2 + mj][rr >> 2][rr & 3];
                s += __shfl_xor(s, 32);
                if ((mp >> 1) == l5) out4[(mp & 1) * 2 + mj] = s;
            }
        }
        *(float4*)(qk + ((size_t)b * N + n) * M + m0 + l5 * 4) =
            float4{out4[0], out4[1], out4[2], out4[3]};
        __syncthreads();
    }
}

// ---------------------------------------------------------------------------
extern "C" void kernel_launch(void* const* d_in, const int* in_sizes, int n_in,
                              void* d_out, int out_size, void* d_ws, size_t ws_size,
                              hipStream_t stream) {
    const float* in    = (const float*)d_in[0];
    const float* w     = (const float*)d_in[1];
    const float* gamma = (const float*)d_in[2];
    const float* beta  = (const float*)d_in[3];
    float* out_qk = (float*)d_out;
    float* out_v  = out_qk + (size_t)B * N * M;

    const size_t WT_BYTES = (size_t)MD * NA * 2;   // 64 MiB
    const size_t IN_BYTES = (size_t)B * NA * 2;    // 8.4 MB
    auto need = [&](int nc) {
        return (size_t)(nc + 1) * C_ELEMS * 4 + WT_BYTES + IN_BYTES;
    };
    int nch = 64;
    bool direct = true;
    if (ws_size < need(64)) nch = 16;
    if (ws_size < need(16)) nch = 8;
    if (ws_size < need(8)) {                       // legacy fallback, no wT
        direct = false;
        nch = 64;
        if (ws_size < (64 + 1) * C_ELEMS * sizeof(float)) nch = 16;
        if (ws_size < (16 + 1) * C_ELEMS * sizeof(float)) nch = 8;
    }
    float*  part = (float*)d_ws;
    float*  vsq  = part + (size_t)nch * C_ELEMS;
    ushort* wT   = (ushort*)(vsq + C_ELEMS);
    ushort* inb  = wT + (size_t)MD * NA;

    if (direct) {
        k0_cvt<<<2048, 256, 0, stream>>>(in, inb);
        k1_mfma<<<dim3(4, nch), 512, 0, stream>>>(in, w, part, wT, nch, 1);
        k2_squash_ln<<<(int)(C_ELEMS / 256), 256, 0, stream>>>(part, gamma, beta,
                                                               vsq, out_v, nch);
        k3_direct<<<dim3(8, 64), 256, 0, stream>>>(wT, inb, vsq, out_qk);
    } else {
        k1_mfma<<<dim3(4, nch), 512, 0, stream>>>(in, w, part, wT, nch, 0);
        k2_squash_ln<<<(int)(C_ELEMS / 256), 256, 0, stream>>>(part, gamma, beta,
                                                               vsq, out_v, nch);
        k3_mfma3<<<dim3(8, 128), 512, 0, stream>>>(in, w, vsq, out_qk);
    }
}

// Round 8
// 145.097 us; speedup vs baseline: 1.0884x; 1.0884x over previous
//
#include <hip/hip_runtime.h>
#include <cstdint>
#include <cstddef>

typedef short bfrag  __attribute__((ext_vector_type(8)));   // 8 bf16 (4 VGPR)
typedef float facc   __attribute__((ext_vector_type(4)));   // 4 f32
typedef float f32x16 __attribute__((ext_vector_type(16)));  // 32x32 acc
typedef float f32x4v __attribute__((ext_vector_type(4)));   // indexable float4

namespace {
constexpr int B = 128, N = 2048, A = 16, M = 64, D = 16;
constexpr int NA = N * A;            // 32768 (GEMM K)
constexpr int MD = M * D;            // 1024  (GEMM N)
constexpr size_t C_ELEMS = (size_t)B * MD;  // 131072
}

static __device__ __forceinline__ ushort f2bf(float x) {  // RNE f32->bf16
    uint u = __float_as_uint(x);
    u += 0x7fffu + ((u >> 16) & 1u);
    return (ushort)(u >> 16);
}
static __device__ __forceinline__ bfrag ld_frag16(const ushort* p) {  // 16B-aligned
    union { uint4 q; bfrag v; } u;
    u.q = *(const uint4*)p;
    return u.v;
}
static __device__ __forceinline__ bfrag ld_frag4(const ushort* p) {   // 4B-aligned
    const uint* q = (const uint*)p;
    union { uint a[4]; bfrag v; } u;
    u.a[0] = q[0]; u.a[1] = q[1]; u.a[2] = q[2]; u.a[3] = q[3];
    return u.v;
}

// ---------------------------------------------------------------------------
// k0: in fp32 -> bf16 in FRAG order: inf[n][bg4][lane64][8]
// thread = (b,n): reads 64B coalesced; writes two 16B groups (l5 = a-half).
// B-frag semantics: B[k=l5*8+j, col=lc] = in[bg*32+lc][n*16 + l5*8 + j]
// ---------------------------------------------------------------------------
__global__ __launch_bounds__(256) void k0_cvt(const float* __restrict__ in,
                                              ushort* __restrict__ inf) {
    const int tid = blockIdx.x * 256 + threadIdx.x;   // B*N = 262144
    const int b = tid >> 11, n = tid & 2047;
    const int bg = b >> 5, lc = b & 31;
    const float* src = in + (size_t)b * NA + n * 16;
    float4 x0 = *(const float4*)(src);
    float4 x1 = *(const float4*)(src + 4);
    float4 x2 = *(const float4*)(src + 8);
    float4 x3 = *(const float4*)(src + 12);
    union { ushort s[8]; uint4 q; } lo, hi;
    lo.s[0] = f2bf(x0.x); lo.s[1] = f2bf(x0.y); lo.s[2] = f2bf(x0.z); lo.s[3] = f2bf(x0.w);
    lo.s[4] = f2bf(x1.x); lo.s[5] = f2bf(x1.y); lo.s[6] = f2bf(x1.z); lo.s[7] = f2bf(x1.w);
    hi.s[0] = f2bf(x2.x); hi.s[1] = f2bf(x2.y); hi.s[2] = f2bf(x2.z); hi.s[3] = f2bf(x2.w);
    hi.s[4] = f2bf(x3.x); hi.s[5] = f2bf(x3.y); hi.s[6] = f2bf(x3.z); hi.s[7] = f2bf(x3.w);
    ushort* dst = inf + (((size_t)n * 4 + bg) * 64 + lc) * 8;
    *(uint4*)dst           = lo.q;                    // lane = lc      (l5=0)
    *(uint4*)(dst + 32*8)  = hi.q;                    // lane = 32+lc   (l5=1)
}

// ---------------------------------------------------------------------------
// k1: split-K bf16 MFMA GEMM. part[chunk][b][md] = sum_{na in chunk} in*w
// + (dump) side-product in FRAG order: wTf[mg8][n][mp4][lane64][8]
//   A-frag semantics: A[row=lc, k=l5*8+j] = w[n][l5*8+j][md], where
//   md = mg*128 + (mp*2 + (lc>>4))*16 + (lc&15).
//   Consecutive threads -> consecutive 16B groups: coalesced global stores;
//   LDS reads stride 33 dwords: conflict-free.
// ---------------------------------------------------------------------------
__global__ __launch_bounds__(512, 2) void k1_mfma(const float* __restrict__ in,
                                                  const float* __restrict__ w,
                                                  float* __restrict__ part,
                                                  ushort* __restrict__ wTf,
                                                  int nch, int dump) {
    const int mdg   = blockIdx.x;
    const int chunk = blockIdx.y;
    const int t     = threadIdx.x;
    const int nap   = NA / nch;
    const int nkt   = nap / 64;
    __shared__ __align__(16) ushort in_t[128 * 72];
    __shared__ __align__(16) ushort w_t[256 * 66];
    const int wv = t >> 6, tl = t & 63;
    const int wb = wv >> 2, wm = wv & 3;
    const int lr = tl & 15, hi = tl >> 4;

    facc acc[4][4];
    #pragma unroll
    for (int i = 0; i < 4; ++i)
        #pragma unroll
        for (int j = 0; j < 4; ++j) acc[i][j] = facc{0.f, 0.f, 0.f, 0.f};

    float4 pin[4], pw[8];
    const int ib  = t >> 4, ik = t & 15;
    const int wk  = t >> 6, wmd = t & 63;

    int na0 = chunk * nap;
    #pragma unroll
    for (int q = 0; q < 4; ++q)
        pin[q] = *(const float4*)(in + (size_t)(q * 32 + ib) * NA + na0 + ik * 4);
    #pragma unroll
    for (int q = 0; q < 8; ++q)
        pw[q] = *(const float4*)(w + (size_t)(na0 + q * 8 + wk) * MD + mdg * 256 + wmd * 4);

    for (int kt = 0; kt < nkt; ++kt) {
        __syncthreads();
        #pragma unroll
        for (int q = 0; q < 4; ++q) {
            union { ushort s[4]; uint2 u; } pk;
            pk.s[0] = f2bf(pin[q].x); pk.s[1] = f2bf(pin[q].y);
            pk.s[2] = f2bf(pin[q].z); pk.s[3] = f2bf(pin[q].w);
            *(uint2*)(&in_t[(q * 32 + ib) * 72 + ik * 4]) = pk.u;
        }
        #pragma unroll
        for (int q = 0; q < 8; ++q) {
            const int krow = q * 8 + wk;
            w_t[(wmd * 4 + 0) * 66 + krow] = f2bf(pw[q].x);
            w_t[(wmd * 4 + 1) * 66 + krow] = f2bf(pw[q].y);
            w_t[(wmd * 4 + 2) * 66 + krow] = f2bf(pw[q].z);
            w_t[(wmd * 4 + 3) * 66 + krow] = f2bf(pw[q].w);
        }
        __syncthreads();
        if (kt + 1 < nkt) {
            const int nan = na0 + 64;
            #pragma unroll
            for (int q = 0; q < 4; ++q)
                pin[q] = *(const float4*)(in + (size_t)(q * 32 + ib) * NA + nan + ik * 4);
            #pragma unroll
            for (int q = 0; q < 8; ++q)
                pw[q] = *(const float4*)(w + (size_t)(nan + q * 8 + wk) * MD + mdg * 256 + wmd * 4);
        }
        if (dump) {   // frag-order dump of this tile (2 mg x 4 n)
            #pragma unroll
            for (int q = 0; q < 4; ++q) {
                const int g = q * 512 + t;
                const int lane2 = g & 63, mp = (g >> 6) & 3;
                const int n_l = (g >> 8) & 3, mg_l = g >> 10;
                const int lc2 = lane2 & 31, l52 = lane2 >> 5;
                const int md_l = mg_l * 128 + (mp * 2 + (lc2 >> 4)) * 16 + (lc2 & 15);
                const int k_l  = n_l * 16 + l52 * 8;
                const uint* s32 = (const uint*)&w_t[md_l * 66 + k_l];
                uint4 o; o.x = s32[0]; o.y = s32[1]; o.z = s32[2]; o.w = s32[3];
                const size_t n = (size_t)(na0 >> 4) + n_l;
                *(uint4*)(wTf + ((((size_t)(mdg * 2 + mg_l) * N + n) * 4 + mp) * 64
                                 + lane2) * 8) = o;
            }
        }
        #pragma unroll
        for (int ks = 0; ks < 2; ++ks) {
            bfrag af[4], bf[4];
            #pragma unroll
            for (int bt = 0; bt < 4; ++bt)
                af[bt] = ld_frag16(&in_t[(wb * 64 + bt * 16 + lr) * 72 + ks * 32 + hi * 8]);
            #pragma unroll
            for (int mt = 0; mt < 4; ++mt)
                bf[mt] = ld_frag4(&w_t[(wm * 64 + mt * 16 + lr) * 66 + ks * 32 + hi * 8]);
            #pragma unroll
            for (int bt = 0; bt < 4; ++bt)
                #pragma unroll
                for (int mt = 0; mt < 4; ++mt)
                    acc[bt][mt] = __builtin_amdgcn_mfma_f32_16x16x32_bf16(
                        af[bt], bf[mt], acc[bt][mt], 0, 0, 0);
        }
        na0 += 64;
    }
    #pragma unroll
    for (int bt = 0; bt < 4; ++bt)
        #pragma unroll
        for (int mt = 0; mt < 4; ++mt) {
            const int b  = wb * 64 + bt * 16 + hi * 4;
            const int md = mdg * 256 + wm * 64 + mt * 16 + lr;
            #pragma unroll
            for (int r = 0; r < 4; ++r)
                part[((size_t)chunk * B + b + r) * MD + md] = acc[bt][mt][r];
        }
}

// ---------------------------------------------------------------------------
// k2: reduce partials -> v_raw -> squash -> v_sq (ws); LayerNorm -> out_v
// ---------------------------------------------------------------------------
__global__ __launch_bounds__(256) void k2_squash_ln(const float* __restrict__ part,
                                                    const float* __restrict__ gamma,
                                                    const float* __restrict__ beta,
                                                    float* __restrict__ v_sq,
                                                    float* __restrict__ out_v,
                                                    int nch) {
    const int idx = blockIdx.x * 256 + threadIdx.x;
    const int d   = idx & 15;
    float s = 0.f;
    for (int c = 0; c < nch; ++c) s += part[(size_t)c * C_ELEMS + idx];
    const float v = s * (1.0f / 64.0f);
    float sq = v * v;
    #pragma unroll
    for (int off = 1; off < 16; off <<= 1) sq += __shfl_xor(sq, off, 16);
    const float f  = sqrtf(sq) / (1.0f + sq);
    const float vs = v * f;
    v_sq[idx] = vs;
    float mu = vs;
    #pragma unroll
    for (int off = 1; off < 16; off <<= 1) mu += __shfl_xor(mu, off, 16);
    mu *= (1.0f / 16.0f);
    const float dd = vs - mu;
    float var = dd * dd;
    #pragma unroll
    for (int off = 1; off < 16; off <<= 1) var += __shfl_xor(var, off, 16);
    var *= (1.0f / 16.0f);
    out_v[idx] = dd / sqrtf(var + 1e-5f) * gamma[d] + beta[d];
}

// ---------------------------------------------------------------------------
// k3 v8: staging-free + fully-coalesced frag loads from frag-ordered ws.
// Per n: 4 A-frag + 1 B-frag b128 loads at lane*16B (1 transaction each),
// 4 MFMA 32x32x16, 64 FMA vs reg-resident vsq, 8 shfl_xor(32), 1 f4 store.
// grid (8 mg, 128 nseg of 16), 256 thr = 4 waves = 4 bg; 4 blocks/CU.
// C layout (HW-verified R5/R6): col=lane&31=b, row=(reg&3)+8*(reg>>2)+4*l5.
// ---------------------------------------------------------------------------
__global__ __launch_bounds__(256, 4) void k3_direct(const ushort* __restrict__ wTf,
                                                    const ushort* __restrict__ inf,
                                                    const float* __restrict__ vsq,
                                                    float* __restrict__ qk) {
    const int mg = blockIdx.x;
    const int m0 = mg * 8;
    const int n0 = blockIdx.y * 16;
    const int t  = threadIdx.x;
    const int bg = t >> 6, lane = t & 63;
    const int lc = lane & 31, l5 = lane >> 5;
    const int b  = bg * 32 + lc;

    f32x4v vr[8][2];   // vr[mm][h][e] = vsq[b][m0+mm][h*8 + 4*l5 + e]
    #pragma unroll
    for (int mm = 0; mm < 8; ++mm) {
        vr[mm][0] = *(const f32x4v*)(vsq + ((size_t)b * M + m0 + mm) * D + 4 * l5);
        vr[mm][1] = *(const f32x4v*)(vsq + ((size_t)b * M + m0 + mm) * D + 8 + 4 * l5);
    }
    // per-lane bases (ushort units)
    const ushort* abase = wTf + ((size_t)mg * N * 4) * 64 * 8 + (size_t)lane * 8;
    const ushort* bbase = inf + ((size_t)bg * 64 + lane) * 8;

    auto lda = [&](int n, int mp) {
        return ld_frag16(abase + ((size_t)n * 4 + mp) * 512);
    };
    auto ldb = [&](int n) {
        return ld_frag16(bbase + (size_t)n * 2048);
    };

    bfrag ac0 = lda(n0, 0), ac1 = lda(n0, 1), ac2 = lda(n0, 2), ac3 = lda(n0, 3);
    bfrag bc  = ldb(n0);

    for (int i = 0; i < 16; ++i) {
        bfrag an0, an1, an2, an3, bn;
        if (i + 1 < 16) {                         // 1-deep reg prefetch
            an0 = lda(n0 + i + 1, 0); an1 = lda(n0 + i + 1, 1);
            an2 = lda(n0 + i + 1, 2); an3 = lda(n0 + i + 1, 3);
            bn  = ldb(n0 + i + 1);
        }
        const int n = n0 + i;
        float out4[4];
        bfrag aa[4] = {ac0, ac1, ac2, ac3};
        #pragma unroll
        for (int mp = 0; mp < 4; ++mp) {
            f32x16 c = {};
            c = __builtin_amdgcn_mfma_f32_32x32x16_bf16(aa[mp], bc, c, 0, 0, 0);
            #pragma unroll
            for (int mj = 0; mj < 2; ++mj) {
                float s = 0.f;
                #pragma unroll
                for (int rr = 0; rr < 8; ++rr)
                    s += c[mj * 8 + rr] * vr[mp * 2 + mj][rr >> 2][rr & 3];
                s += __shfl_xor(s, 32);           // add other d-half
                if ((mp >> 1) == l5) out4[(mp & 1) * 2 + mj] = s;
            }
        }
        *(float4*)(qk + ((size_t)b * N + n) * M + m0 + l5 * 4) =
            float4{out4[0], out4[1], out4[2], out4[3]};
        if (i + 1 < 16) { ac0 = an0; ac1 = an1; ac2 = an2; ac3 = an3; bc = bn; }
    }
}

// ---------------------------------------------------------------------------
// k3 v6 fallback (if ws too small for wTf): R6's LDS-staged version.
// ---------------------------------------------------------------------------
__global__ __launch_bounds__(512, 4) void k3_mfma3(const float* __restrict__ in,
                                                   const float* __restrict__ w,
                                                   const float* __restrict__ vsq,
                                                   float* __restrict__ qk) {
    constexpr int WP = 24;
    const int m0 = blockIdx.x * 8;
    const int n0 = blockIdx.y * 16;
    const int t  = threadIdx.x;
    const int wv = t >> 6;
    const int nh = wv >> 2, bg = wv & 3;
    const int lane = t & 63;
    const int lc = lane & 31, l5 = lane >> 5;
    const int b  = bg * 32 + lc;
    __shared__ __align__(16) ushort wt[2][2][4 * 32 * WP];
    __shared__ __align__(16) ushort it[2][2][128 * WP];
    f32x4v vr[8][2];
    #pragma unroll
    for (int mm = 0; mm < 8; ++mm) {
        vr[mm][0] = *(const f32x4v*)(vsq + ((size_t)b * M + m0 + mm) * D + 4 * l5);
        vr[mm][1] = *(const f32x4v*)(vsq + ((size_t)b * M + m0 + mm) * D + 8 + 4 * l5);
    }
    const int s_nn = t >> 8, r = t & 255;
    const int wa1 = r & 7, wd4 = (r >> 3) & 3, wm_ = r >> 5;
    const int ib_ = r >> 1, iq = r & 1;
    float4 pw[2], pi[2];
    auto ldg = [&](int ph) {
        const int n = n0 + ph * 2 + s_nn;
        #pragma unroll
        for (int j = 0; j < 2; ++j)
            pw[j] = *(const float4*)(
                w + ((size_t)(n * A + wa1 * 2 + j) * M + m0 + wm_) * D + wd4 * 4);
        #pragma unroll
        for (int j = 0; j < 2; ++j)
            pi[j] = *(const float4*)(in + (size_t)ib_ * NA + n * A + iq * 8 + j * 4);
    };
    auto stg = [&](int p) {
        ushort* wb_ = &wt[p][s_nn][((wm_ >> 1) * 32 + (wm_ & 1) * 16) * WP];
        #pragma unroll
        for (int k = 0; k < 4; ++k) {
            union { ushort s[2]; uint u; } v;
            v.s[0] = f2bf(pw[0][k]);
            v.s[1] = f2bf(pw[1][k]);
            *(uint*)(&wb_[(wd4 * 4 + k) * WP + wa1 * 2]) = v.u;
        }
        union { ushort s[8]; uint4 q; } pk;
        #pragma unroll
        for (int j = 0; j < 2; ++j) {
            pk.s[j * 4 + 0] = f2bf(pi[j].x); pk.s[j * 4 + 1] = f2bf(pi[j].y);
            pk.s[j * 4 + 2] = f2bf(pi[j].z); pk.s[j * 4 + 3] = f2bf(pi[j].w);
        }
        *(uint4*)(&it[p][s_nn][ib_ * WP + iq * 8]) = pk.q;
    };
    ldg(0); stg(0); ldg(1);
    __syncthreads();
    for (int ph = 0; ph < 8; ++ph) {
        const int p = ph & 1;
        if (ph < 7) stg(p ^ 1);
        if (ph < 6) ldg(ph + 2);
        const int n = n0 + ph * 2 + nh;
        const bfrag bf = ld_frag16(&it[p][nh][b * WP + l5 * 8]);
        float out4[4];
        #pragma unroll
        for (int mp = 0; mp < 4; ++mp) {
            const bfrag af = ld_frag16(&wt[p][nh][(mp * 32 + lc) * WP + l5 * 8]);
            f32x16 c = {};
            c = __builtin_amdgcn_mfma_f32_32x32x16_bf16(af, bf, c, 0, 0, 0);
            #pragma unroll
            for (int mj = 0; mj < 2; ++mj) {
                float s = 0.f;
                #pragma unroll
                for (int rr = 0; rr < 8; ++rr)
                    s += c[mj * 8 + rr] * vr[mp * 2 + mj][rr >> 2][rr & 3];
                s += __shfl_xor(s, 32);
                if ((mp >> 1) == l5) out4[(mp & 1) * 2 + mj] = s;
            }
        }
        *(float4*)(qk + ((size_t)b * N + n) * M + m0 + l5 * 4) =
            float4{out4[0], out4[1], out4[2], out4[3]};
        __syncthreads();
    }
}

// ---------------------------------------------------------------------------
extern "C" void kernel_launch(void* const* d_in, const int* in_sizes, int n_in,
                              void* d_out, int out_size, void* d_ws, size_t ws_size,
                              hipStream_t stream) {
    const float* in    = (const float*)d_in[0];
    const float* w     = (const float*)d_in[1];
    const float* gamma = (const float*)d_in[2];
    const float* beta  = (const float*)d_in[3];
    float* out_qk = (float*)d_out;
    float* out_v  = out_qk + (size_t)B * N * M;

    const size_t WT_BYTES = (size_t)MD * NA * 2;   // 64 MiB (frag order)
    const size_t IN_BYTES = (size_t)B * NA * 2;    // 8.4 MB (frag order)
    auto need = [&](int nc) {
        return (size_t)(nc + 1) * C_ELEMS * 4 + WT_BYTES + IN_BYTES;
    };
    int nch = 64;
    bool direct = true;
    if (ws_size < need(64)) nch = 16;
    if (ws_size < need(16)) nch = 8;
    if (ws_size < need(8)) {                       // legacy fallback, no wTf
        direct = false;
        nch = 64;
        if (ws_size < (64 + 1) * C_ELEMS * sizeof(float)) nch = 16;
        if (ws_size < (16 + 1) * C_ELEMS * sizeof(float)) nch = 8;
    }
    float*  part = (float*)d_ws;
    float*  vsq  = part + (size_t)nch * C_ELEMS;
    ushort* wTf  = (ushort*)(vsq + C_ELEMS);
    ushort* inf  = wTf + (size_t)MD * NA;

    if (direct) {
        k0_cvt<<<(B * N) / 256, 256, 0, stream>>>(in, inf);
        k1_mfma<<<dim3(4, nch), 512, 0, stream>>>(in, w, part, wTf, nch, 1);
        k2_squash_ln<<<(int)(C_ELEMS / 256), 256, 0, stream>>>(part, gamma, beta,
                                                               vsq, out_v, nch);
        k3_direct<<<dim3(8, 128), 256, 0, stream>>>(wTf, inf, vsq, out_qk);
    } else {
        k1_mfma<<<dim3(4, nch), 512, 0, stream>>>(in, w, part, wTf, nch, 0);
        k2_squash_ln<<<(int)(C_ELEMS / 256), 256, 0, stream>>>(part, gamma, beta,
                                                               vsq, out_v, nch);
        k3_mfma3<<<dim3(8, 128), 512, 0, stream>>>(in, w, vsq, out_qk);
    }
}